// Round 7
// baseline (192.880 us; speedup 1.0000x reference)
//
#include <hip/hip_runtime.h>

// CovarianceLayer: x [B=64, C=4, T=8192, M=16] fp32 -> cov [B, C, 16, 16] fp32
// cov = (P - S S^T / T) / (T-1),  P = X^T X via mfma_f32_16x16x32_bf16.
//
// R7: DISCRIMINATING PROBE. R3-R6 (scalar / vectorized / deep-prefetch /
// many-small-blocks) all pin at ~53 us = 2.5 TB/s aggregate read, invariant
// to every per-CU lever. This round halves the CU count (128 blocks x 1024
// threads, 2 bc per block, inner loop byte-identical to R5):
//   outcome A: total ~186 us  -> aggregate read-path cap (CU-independent)
//   outcome B: total ~238 us, kernel ~106 us visible in top-5 with counters
//              -> per-CU cap (~10 GB/s/CU), attack per-CU concurrency next.

constexpr int T_DIM = 8192;
constexpr int M_DIM = 16;
constexpr int BLOCK = 1024;                 // 16 waves
constexpr int BC_PER_BLOCK = 2;             // probe: half grid, 2 bc each
constexpr int NWAVE = BLOCK / 64;           // 16
constexpr int T_PER_WAVE = T_DIM / NWAVE;   // 512 rows
constexpr int ROUNDS = T_PER_WAVE / 32;     // 16 rounds of 32 rows
constexpr int PF = 4;                       // prefetch depth

using bf16x8 = __attribute__((ext_vector_type(8))) short;
using f32x4  = __attribute__((ext_vector_type(4))) float;

static __device__ inline unsigned pack_bf2(float lo, float hi) {
    // RNE fp32->bf16 for both, packed lo | hi<<16 (finite normal inputs)
    union { float f; unsigned u; } a{lo}, b{hi};
    unsigned ra = a.u + 0x7fffu + ((a.u >> 16) & 1u);
    unsigned rb = b.u + 0x7fffu + ((b.u >> 16) & 1u);
    return (ra >> 16) | (rb & 0xffff0000u);
}

__global__ __launch_bounds__(BLOCK)
void cov_kernel(const float* __restrict__ x, float* __restrict__ out) {
    const int tid  = threadIdx.x;
    const int wave = tid >> 6;
    const int lane = tid & 63;

    // staging roles: lane covers rows 2rg..2rg+1 (round-local), cols 4g..4g+3
    const int rg = lane & 15;
    const int g  = lane >> 4;
    // MFMA roles: col = m, k-rows q*8..q*8+7 (layout verified R3-R6)
    const int q  = lane >> 4;
    const int m  = lane & 15;

    __shared__ __align__(16) unsigned stage[NWAVE][2][256]; // 2x 1KB per wave
    __shared__ float Pred[NWAVE][256];
    __shared__ float Sred[NWAVE][M_DIM];
    __shared__ float Stot[M_DIM];

    // LDS write offsets: granule = qw*16 + (col ^ qw), dword-in-granule = dq
    const int qw = rg >> 2, dq = rg & 3;
    // LDS read pointer: granule = q*16 + (m ^ q), 16B each
    const int roff = (q * 16 + (m ^ q)) * 4;

    for (int sub = 0; sub < BC_PER_BLOCK; ++sub) {
        const int bc = blockIdx.x * BC_PER_BLOCK + sub;
        const float4* __restrict__ xin =
            (const float4*)(x + (size_t)bc * (T_DIM * M_DIM));

        // float4 index of (row, segment g); round stride = 32 rows = 128 f4.
        const int idx0 = (wave * T_PER_WAVE + 2 * rg) * 4 + g;

        f32x4 acc = {0.f, 0.f, 0.f, 0.f};
        float s0 = 0.f, s1 = 0.f, s2 = 0.f, s3 = 0.f;

        float4 buf0[PF], buf1[PF];
#pragma unroll
        for (int r = 0; r < PF; ++r) {
            buf0[r] = xin[idx0 + r * 128];
            buf1[r] = xin[idx0 + r * 128 + 4];
        }

#pragma unroll
        for (int r = 0; r < ROUNDS; ++r) {
            const float4 a0 = buf0[r % PF];
            const float4 a1 = buf1[r % PF];
            if (r + PF < ROUNDS) {
                buf0[r % PF] = xin[idx0 + (r + PF) * 128];
                buf1[r % PF] = xin[idx0 + (r + PF) * 128 + 4];
            }

            s0 += a0.x + a1.x;  s1 += a0.y + a1.y;
            s2 += a0.z + a1.z;  s3 += a0.w + a1.w;
            unsigned* wb = &stage[wave][r & 1][0];
            wb[(qw * 16 + ((4 * g + 0) ^ qw)) * 4 + dq] = pack_bf2(a0.x, a1.x);
            wb[(qw * 16 + ((4 * g + 1) ^ qw)) * 4 + dq] = pack_bf2(a0.y, a1.y);
            wb[(qw * 16 + ((4 * g + 2) ^ qw)) * 4 + dq] = pack_bf2(a0.z, a1.z);
            wb[(qw * 16 + ((4 * g + 3) ^ qw)) * 4 + dq] = pack_bf2(a0.w, a1.w);
            bf16x8 frag = *(const bf16x8*)&stage[wave][r & 1][roff];
            acc = __builtin_amdgcn_mfma_f32_16x16x32_bf16(frag, frag, acc,
                                                          0, 0, 0);
        }

        // Wave column sums: reduce over rg; lanes rg==0 hold cols 4g..4g+3.
#pragma unroll
        for (int off = 1; off <= 8; off <<= 1) {
            s0 += __shfl_xor(s0, off, 64);
            s1 += __shfl_xor(s1, off, 64);
            s2 += __shfl_xor(s2, off, 64);
            s3 += __shfl_xor(s3, off, 64);
        }
        if (rg == 0) {
            Sred[wave][4 * g + 0] = s0;
            Sred[wave][4 * g + 1] = s1;
            Sred[wave][4 * g + 2] = s2;
            Sred[wave][4 * g + 3] = s3;
        }

        // Per-wave partial P. C/D layout: col = m, row = q*4 + reg.
#pragma unroll
        for (int r = 0; r < 4; ++r)
            Pred[wave][(q * 4 + r) * M_DIM + m] = acc[r];
        __syncthreads();

        if (tid < M_DIM) {
            float s = 0.f;
#pragma unroll
            for (int w = 0; w < NWAVE; ++w) s += Sred[w][tid];
            Stot[tid] = s;
        }
        __syncthreads();

        if (tid < 256) {
            float P = 0.f;
#pragma unroll
            for (int w = 0; w < NWAVE; ++w) P += Pred[w][tid];
            const int mi = tid >> 4;
            const int ni = tid & 15;
            const float cov = (P - Stot[mi] * Stot[ni] * (1.0f / (float)T_DIM))
                            * (1.0f / (float)(T_DIM - 1));
            out[(size_t)bc * 256 + tid] = cov;
        }
        __syncthreads();   // protect Pred/Sred reuse in next sub-iteration
    }
}

extern "C" void kernel_launch(void* const* d_in, const int* in_sizes, int n_in,
                              void* d_out, int out_size, void* d_ws, size_t ws_size,
                              hipStream_t stream) {
    const float* x = (const float*)d_in[0];
    float* out = (float*)d_out;
    const int n_bc = in_sizes[0] / (T_DIM * M_DIM);   // B*C = 256
    cov_kernel<<<dim3(n_bc / BC_PER_BLOCK), dim3(BLOCK), 0, stream>>>(x, out);
}

// Round 9
// 181.401 us; speedup vs baseline: 1.0633x; 1.0633x over previous
//
#include <hip/hip_runtime.h>

// CovarianceLayer: x [B=64, C=4, T=8192, M=16] fp32 -> cov [B, C, 16, 16] fp32
// cov = (P - S S^T / T) / (T-1),  P = X^T X via mfma_f32_16x16x32_bf16.
//
// R9 = R8 with the compile fix: __builtin_nontemporal_load requires a
// native clang vector type, not HIP's float4 class -> stream through
// ext_vector_type(4) float.
//
// Evidence so far: R3-R7 all pin at ~2.5 TB/s aggregate read, invariant to
// vectorization (R4), prefetch depth (R5), decomposition (R6), and CU count
// (R7: half the CUs -> +10% time only). Best read rate ever measured on this
// part is ~3.15 TB/s (m13 copy read-half); pure write does 6.9. The input is
// a 134 MB read-once stream with zero reuse -> NT loads skip cache
// allocation, the last untried source-level lever on the read path.
//
// Per 32-row round: 2 coalesced NT float4 loads/lane, fp32 column sums
// (exact mean term), bf16 pack, swizzled wave-private LDS transpose (writes
// 2 lanes/bank = free, reads conflict-free b128), 1 MFMA (A==B fragment).
// No barriers in the main loop; block combine + finalize as in R3-R5.

constexpr int T_DIM = 8192;
constexpr int M_DIM = 16;
constexpr int BLOCK = 1024;                 // 16 waves, 1 block per (b,c)
constexpr int NWAVE = BLOCK / 64;           // 16
constexpr int T_PER_WAVE = T_DIM / NWAVE;   // 512 rows
constexpr int ROUNDS = T_PER_WAVE / 32;     // 16 rounds of 32 rows
constexpr int PF = 4;                       // prefetch depth

using bf16x8 = __attribute__((ext_vector_type(8))) short;
using f32x4  = __attribute__((ext_vector_type(4))) float;   // native vector

static __device__ inline unsigned pack_bf2(float lo, float hi) {
    // RNE fp32->bf16 for both, packed lo | hi<<16 (finite normal inputs)
    union { float f; unsigned u; } a{lo}, b{hi};
    unsigned ra = a.u + 0x7fffu + ((a.u >> 16) & 1u);
    unsigned rb = b.u + 0x7fffu + ((b.u >> 16) & 1u);
    return (ra >> 16) | (rb & 0xffff0000u);
}

__global__ __launch_bounds__(BLOCK)
void cov_kernel(const float* __restrict__ x, float* __restrict__ out) {
    const int bc   = blockIdx.x;
    const int tid  = threadIdx.x;
    const int wave = tid >> 6;
    const int lane = tid & 63;

    // staging roles: lane covers rows 2rg..2rg+1 (round-local), cols 4g..4g+3
    const int rg = lane & 15;
    const int g  = lane >> 4;
    // MFMA roles: col = m, k-rows q*8..q*8+7 (layout verified R3-R7)
    const int q  = lane >> 4;
    const int m  = lane & 15;

    __shared__ __align__(16) unsigned stage[NWAVE][2][256]; // 2x 1KB per wave
    __shared__ float Pred[NWAVE][256];
    __shared__ float Sred[NWAVE][M_DIM];
    __shared__ float Stot[M_DIM];

    const f32x4* __restrict__ xin =
        (const f32x4*)(x + (size_t)bc * (T_DIM * M_DIM));

    // float4 index of (row, segment g); round stride = 32 rows = 128 f4.
    const int idx0 = (wave * T_PER_WAVE + 2 * rg) * 4 + g;

    // LDS write offsets: granule = qw*16 + (col ^ qw), dword-in-granule = dq
    const int qw = rg >> 2, dq = rg & 3;
    // LDS read pointer: granule = q*16 + (m ^ q), 16B each
    const int roff = (q * 16 + (m ^ q)) * 4;

    f32x4 acc = {0.f, 0.f, 0.f, 0.f};
    float s0 = 0.f, s1 = 0.f, s2 = 0.f, s3 = 0.f;

    // Rotating prefetch buffers: rounds r..r+PF-1 in flight at all times.
    f32x4 buf0[PF], buf1[PF];
#pragma unroll
    for (int r = 0; r < PF; ++r) {
        buf0[r] = __builtin_nontemporal_load(&xin[idx0 + r * 128]);
        buf1[r] = __builtin_nontemporal_load(&xin[idx0 + r * 128 + 4]);
    }

#pragma unroll
    for (int r = 0; r < ROUNDS; ++r) {
        const f32x4 a0 = buf0[r % PF];
        const f32x4 a1 = buf1[r % PF];
        if (r + PF < ROUNDS) {
            buf0[r % PF] =
                __builtin_nontemporal_load(&xin[idx0 + (r + PF) * 128]);
            buf1[r % PF] =
                __builtin_nontemporal_load(&xin[idx0 + (r + PF) * 128 + 4]);
        }

        s0 += a0[0] + a1[0];  s1 += a0[1] + a1[1];
        s2 += a0[2] + a1[2];  s3 += a0[3] + a1[3];
        unsigned* wb = &stage[wave][r & 1][0];
        wb[(qw * 16 + ((4 * g + 0) ^ qw)) * 4 + dq] = pack_bf2(a0[0], a1[0]);
        wb[(qw * 16 + ((4 * g + 1) ^ qw)) * 4 + dq] = pack_bf2(a0[1], a1[1]);
        wb[(qw * 16 + ((4 * g + 2) ^ qw)) * 4 + dq] = pack_bf2(a0[2], a1[2]);
        wb[(qw * 16 + ((4 * g + 3) ^ qw)) * 4 + dq] = pack_bf2(a0[3], a1[3]);
        bf16x8 frag = *(const bf16x8*)&stage[wave][r & 1][roff];
        acc = __builtin_amdgcn_mfma_f32_16x16x32_bf16(frag, frag, acc, 0, 0, 0);
    }

    // Wave column sums: reduce over rg (lane bits 0..3); lanes rg==0 hold
    // cols 4g..4g+3.
#pragma unroll
    for (int off = 1; off <= 8; off <<= 1) {
        s0 += __shfl_xor(s0, off, 64);
        s1 += __shfl_xor(s1, off, 64);
        s2 += __shfl_xor(s2, off, 64);
        s3 += __shfl_xor(s3, off, 64);
    }
    if (rg == 0) {
        Sred[wave][4 * g + 0] = s0;
        Sred[wave][4 * g + 1] = s1;
        Sred[wave][4 * g + 2] = s2;
        Sred[wave][4 * g + 3] = s3;
    }

    // Per-wave partial P into LDS. C/D layout: col = m, row = q*4 + reg.
#pragma unroll
    for (int r = 0; r < 4; ++r)
        Pred[wave][(q * 4 + r) * M_DIM + m] = acc[r];
    __syncthreads();

    if (tid < M_DIM) {
        float s = 0.f;
#pragma unroll
        for (int w = 0; w < NWAVE; ++w) s += Sred[w][tid];
        Stot[tid] = s;
    }
    __syncthreads();

    if (tid < 256) {
        float P = 0.f;
#pragma unroll
        for (int w = 0; w < NWAVE; ++w) P += Pred[w][tid];
        const int mi = tid >> 4;
        const int ni = tid & 15;
        const float cov = (P - Stot[mi] * Stot[ni] * (1.0f / (float)T_DIM))
                        * (1.0f / (float)(T_DIM - 1));
        out[(size_t)bc * 256 + tid] = cov;
    }
}

extern "C" void kernel_launch(void* const* d_in, const int* in_sizes, int n_in,
                              void* d_out, int out_size, void* d_ws, size_t ws_size,
                              hipStream_t stream) {
    const float* x = (const float*)d_in[0];
    float* out = (float*)d_out;
    const int n_bc = in_sizes[0] / (T_DIM * M_DIM);   // B*C = 256
    cov_kernel<<<dim3(n_bc), dim3(BLOCK), 0, stream>>>(x, out);
}